// Round 5
// baseline (58.756 us; speedup 1.0000x reference)
//
#include <hip/hip_runtime.h>

#define W 256
#define HTOT 1280            // num_img * H = 5 * 256
#define RR 8                 // output rows per wave (stripe height)
#define SPB (HTOT / RR)      // 160 stripes per batch
#define BS 64                // batch size
#define WPB 4                // waves per block (256 threads)
#define BLKPB (SPB / WPB)    // 40 blocks per batch
#define NC (BLKPB * 3)       // 120 candidates per batch
#define NEG_FILL -1e9f

struct Cand { float v; int i; };

#define NINF_BITS ((int)0xFF800000)

// DPP wave-wide lane shifts (single VALU op, no DS latency).
// wave_shr:1 (0x138): lane i <- lane i-1 ; lane 0 gets `old` (-inf).
// wave_shl:1 (0x130): lane i <- lane i+1 ; lane 63 gets `old` (-inf).
__device__ __forceinline__ float lane_up1(float x) {   // from lane-1
    return __int_as_float(__builtin_amdgcn_update_dpp(
        NINF_BITS, __float_as_int(x), 0x138, 0xF, 0xF, false));
}
__device__ __forceinline__ float lane_dn1(float x) {   // from lane+1
    return __int_as_float(__builtin_amdgcn_update_dpp(
        NINF_BITS, __float_as_int(x), 0x130, 0xF, 0xF, false));
}

__device__ __forceinline__ bool better(float av, int ai, float bv, int bi) {
    // larger value wins; tie -> smaller flat index (XLA top_k tie-break)
    return (av > bv) || (av == bv && ai < bi);
}

__device__ __forceinline__ void merge3(float cv, int ci,
                                       float& v0, int& i0,
                                       float& v1, int& i1,
                                       float& v2, int& i2) {
    if (better(cv, ci, v2, i2)) {
        if (better(cv, ci, v1, i1)) {
            v2 = v1; i2 = i1;
            if (better(cv, ci, v0, i0)) { v1 = v0; i1 = i0; v0 = cv; i0 = ci; }
            else { v1 = cv; i1 = ci; }
        } else { v2 = cv; i2 = ci; }
    }
}

// 4 independent 64-lane waves per block; each wave owns one 8-row stripe.
// Thread owns 4 columns; halo via DPP; 4-row software pipeline of float4 loads.
__global__ __launch_bounds__(64 * WPB) void peaks_phase1(const float* __restrict__ hm,
                                                         Cand* __restrict__ ws) {
    const int lane = threadIdx.x & 63;
    const int wv   = threadIdx.x >> 6;
    const int g = blockIdx.x * WPB + wv;   // global stripe id (blocks never cross batches)
    const int b = g / SPB;                 // batch (wave-uniform)
    const int s = g - b * SPB;             // stripe
    const int r0 = s * RR;
    const float NINF = -__builtin_inff();

    const float* base = hm + (size_t)b * (size_t)(HTOT * W) + lane * 4;

    auto LOADROW = [&](int gr) -> float4 {
        float4 v;
        if ((unsigned)gr < (unsigned)HTOT) {
            v = *(const float4*)(base + (size_t)gr * W);
        } else {
            v.x = NINF; v.y = NINF; v.z = NINF; v.w = NINF;
        }
        return v;
    };

    // vertical chains: h[k][j] = horizontal 5-max of row (cur-4+k), col j
    float h[5][4];
    float raw0[4], raw1[4], raw2[4];
    #pragma unroll
    for (int k = 0; k < 5; ++k) {
        h[k][0] = NINF; h[k][1] = NINF; h[k][2] = NINF; h[k][3] = NINF;
    }
    #pragma unroll
    for (int j = 0; j < 4; ++j) { raw0[j] = NINF; raw1[j] = NINF; raw2[j] = NINF; }

    float v0 = NINF, v1 = NINF, v2 = NINF;
    int   i0 = 0x7fffffff, i1 = 0x7fffffff, i2 = 0x7fffffff;

    // software pipeline: 4 rows in flight
    float4 p0 = LOADROW(r0 - 2);
    float4 p1 = LOADROW(r0 - 1);
    float4 p2 = LOADROW(r0);
    float4 p3 = LOADROW(r0 + 1);

    #pragma unroll
    for (int r = 0; r < RR + 4; ++r) {
        float4 cur = p0;
        p0 = p1; p1 = p2; p2 = p3;
        if (r < RR) p3 = LOADROW(r0 + 2 + r);   // statically elided for r>=RR

        // halo from neighbor lanes via DPP (boundary lanes auto-fill -inf)
        float L1 = lane_up1(cur.w);    // col c0-1
        float L2 = lane_up1(cur.z);    // col c0-2
        float R1 = lane_dn1(cur.x);    // col c0+4
        float R2 = lane_dn1(cur.y);    // col c0+5

        // horizontal 5-window maxes for the 4 owned columns
        float myz   = fmaxf(cur.y, cur.z);
        float mxyz  = fmaxf(cur.x, myz);
        float myzw  = fmaxf(myz, cur.w);
        float mxyzw = fmaxf(mxyz, cur.w);
        float hm0 = fmaxf(fmaxf(L2, L1), mxyz);          // cols c-2..c+2 for j=0
        float hm1 = fmaxf(L1, mxyzw);                    // j=1
        float hm2 = fmaxf(mxyzw, R1);                    // j=2
        float hm3 = fmaxf(myzw, fmaxf(R1, R2));          // j=3

        // shift vertical chains (renamed away by full unroll)
        #pragma unroll
        for (int k = 0; k < 4; ++k) {
            h[k][0] = h[k + 1][0]; h[k][1] = h[k + 1][1];
            h[k][2] = h[k + 1][2]; h[k][3] = h[k + 1][3];
        }
        h[4][0] = hm0; h[4][1] = hm1; h[4][2] = hm2; h[4][3] = hm3;
        #pragma unroll
        for (int j = 0; j < 4; ++j) { raw0[j] = raw1[j]; raw1[j] = raw2[j]; }
        raw2[0] = cur.x; raw2[1] = cur.y; raw2[2] = cur.z; raw2[3] = cur.w;

        if (r >= 4) {
            const int rout = r0 + r - 4;
            #pragma unroll
            for (int j = 0; j < 4; ++j) {
                float wmax = fmaxf(fmaxf(fmaxf(h[0][j], h[1][j]),
                                         fmaxf(h[2][j], h[3][j])), h[4][j]);
                float rv = raw0[j];
                // exact-equality peak test; strict > keeps earliest equal value
                // first within a thread (matches smallest-index tie-break).
                if (rv == wmax && rv > v2) {
                    int idx = rout * W + lane * 4 + j;
                    if (rv > v1) {
                        v2 = v1; i2 = i1;
                        if (rv > v0) { v1 = v0; i1 = i0; v0 = rv; i0 = idx; }
                        else         { v1 = rv; i1 = idx; }
                    } else { v2 = rv; i2 = idx; }
                }
            }
        }
    }

    // wave butterfly reduction of per-thread top-3 (full tie-break comparator)
    #pragma unroll
    for (int m = 1; m < 64; m <<= 1) {
        float a0 = __shfl_xor(v0, m), a1 = __shfl_xor(v1, m), a2 = __shfl_xor(v2, m);
        int   c0 = __shfl_xor(i0, m), c1 = __shfl_xor(i1, m), c2 = __shfl_xor(i2, m);
        merge3(a0, c0, v0, i0, v1, i1, v2, i2);
        merge3(a1, c1, v0, i0, v1, i1, v2, i2);
        merge3(a2, c2, v0, i0, v1, i1, v2, i2);
    }

    // cross-wave merge inside the block (tiny LDS), one candidate-triple out
    __shared__ float sv[WPB * 3];
    __shared__ int   si[WPB * 3];
    if (lane == 0) {
        sv[wv * 3 + 0] = v0; sv[wv * 3 + 1] = v1; sv[wv * 3 + 2] = v2;
        si[wv * 3 + 0] = i0; si[wv * 3 + 1] = i1; si[wv * 3 + 2] = i2;
    }
    __syncthreads();
    if (threadIdx.x == 0) {
        float b0 = sv[0], b1 = sv[1], b2 = sv[2];
        int   j0 = si[0], j1 = si[1], j2 = si[2];
        #pragma unroll
        for (int q = 3; q < WPB * 3; ++q) merge3(sv[q], si[q], b0, j0, b1, j1, b2, j2);
        Cand* o = ws + (size_t)blockIdx.x * 3;
        o[0].v = b0; o[0].i = j0;
        o[1].v = b1; o[1].i = j1;
        o[2].v = b2; o[2].i = j2;
    }
}

__global__ __launch_bounds__(128) void peaks_phase2(const Cand* __restrict__ ws,
                                                    float* __restrict__ out) {
    const int b = blockIdx.x;
    const int t = threadIdx.x;
    const float NINF = -__builtin_inff();

    float v0 = NINF, v1 = NINF, v2 = NINF;
    int   i0 = 0x7fffffff, i1 = 0x7fffffff, i2 = 0x7fffffff;
    if (t < NC) {
        Cand e = ws[(size_t)b * NC + t];
        v0 = e.v; i0 = e.i;
    }

    __shared__ float rv[128][3];
    __shared__ int   ri[128][3];
    rv[t][0] = v0; rv[t][1] = v1; rv[t][2] = v2;
    ri[t][0] = i0; ri[t][1] = i1; ri[t][2] = i2;
    __syncthreads();
    for (int s = 64; s > 0; s >>= 1) {
        if (t < s) {
            merge3(rv[t + s][0], ri[t + s][0], v0, i0, v1, i1, v2, i2);
            merge3(rv[t + s][1], ri[t + s][1], v0, i0, v1, i1, v2, i2);
            merge3(rv[t + s][2], ri[t + s][2], v0, i0, v1, i1, v2, i2);
            rv[t][0] = v0; rv[t][1] = v1; rv[t][2] = v2;
            ri[t][0] = i0; ri[t][1] = i1; ri[t][2] = i2;
        }
        __syncthreads();
    }

    if (t == 0) {
        // positions [64,3,3] at 0 ; scores [64,3] at 576 ; mask [64,3] at 768
        float* pos = out + (size_t)b * 9;
        float* sco = out + 576 + (size_t)b * 3;
        float* msk = out + 768 + (size_t)b * 3;

        pos[0] = (float)(i0 >> 16);
        pos[1] = (float)((i0 >> 8) & 255);
        pos[2] = (float)(i0 & 255);
        sco[0] = v0;
        msk[0] = (v0 > -1e30f) ? 1.0f : 0.0f;

        pos[3] = (float)(i1 >> 16);
        pos[4] = (float)((i1 >> 8) & 255);
        pos[5] = (float)(i1 & 255);
        sco[1] = v1;
        msk[1] = (v1 > -1e30f) ? 1.0f : 0.0f;

        pos[6] = (float)(i2 >> 16);
        pos[7] = (float)((i2 >> 8) & 255);
        pos[8] = (float)(i2 & 255);
        sco[2] = v2;
        msk[2] = (v2 > -1e30f) ? 1.0f : 0.0f;
    }
}

extern "C" void kernel_launch(void* const* d_in, const int* in_sizes, int n_in,
                              void* d_out, int out_size, void* d_ws, size_t ws_size,
                              hipStream_t stream) {
    const float* hm = (const float*)d_in[0];
    float* out = (float*)d_out;
    Cand* ws = (Cand*)d_ws;  // 64*40*3*8 = 61440 bytes

    peaks_phase1<<<(BS * SPB) / WPB, 64 * WPB, 0, stream>>>(hm, ws);
    peaks_phase2<<<BS, 128, 0, stream>>>(ws, out);
}

// Round 6
// 31.364 us; speedup vs baseline: 1.8734x; 1.8734x over previous
//
#include <hip/hip_runtime.h>

#define W 256
#define HTOT 1280            // num_img * H = 5 * 256
#define RR 16                // output rows per wave
#define SPB (HTOT / RR)      // 80 stripes per batch
#define BS 64                // batch size
#define NC (SPB * 3)         // 240 candidates per batch
#define NEG_FILL -1e9f

struct Cand { float v; int i; };

#define NINF_BITS ((int)0xFF800000)
#define IMAX 0x7fffffff

// ---------- DPP primitives (pure VALU, no DS, no LDS) ----------
// wave_shr:1 (0x138): lane i <- lane i-1 ; invalid lanes get `old` (-inf).
// wave_shl:1 (0x130): lane i <- lane i+1.
__device__ __forceinline__ float lane_up1(float x) {
    return __int_as_float(__builtin_amdgcn_update_dpp(
        NINF_BITS, __float_as_int(x), 0x138, 0xF, 0xF, false));
}
__device__ __forceinline__ float lane_dn1(float x) {
    return __int_as_float(__builtin_amdgcn_update_dpp(
        NINF_BITS, __float_as_int(x), 0x130, 0xF, 0xF, false));
}

template <int CTRL>
__device__ __forceinline__ float fmax_dpp(float x) {
    int s = __builtin_amdgcn_update_dpp(NINF_BITS, __float_as_int(x),
                                        CTRL, 0xF, 0xF, false);
    return fmaxf(x, __int_as_float(s));
}
template <int CTRL>
__device__ __forceinline__ int imin_dpp(int x) {
    int s = __builtin_amdgcn_update_dpp(IMAX, x, CTRL, 0xF, 0xF, false);
    return (s < x) ? s : x;
}

// wave64 max -> lane 63 (row_shr 1,2,4,8 then row_bcast15, row_bcast31)
__device__ __forceinline__ float wave_fmax_l63(float x) {
    x = fmax_dpp<0x111>(x);
    x = fmax_dpp<0x112>(x);
    x = fmax_dpp<0x114>(x);
    x = fmax_dpp<0x118>(x);
    x = fmax_dpp<0x142>(x);
    x = fmax_dpp<0x143>(x);
    return x;
}
__device__ __forceinline__ int wave_imin_l63(int x) {
    x = imin_dpp<0x111>(x);
    x = imin_dpp<0x112>(x);
    x = imin_dpp<0x114>(x);
    x = imin_dpp<0x118>(x);
    x = imin_dpp<0x142>(x);
    x = imin_dpp<0x143>(x);
    return x;
}

// Extract wave-wide top-3 from per-thread sorted lists (v0>=v1>=v2, index
// tie-break: within a thread v0 holds the smallest index among equals).
// Results are wave-uniform in outv/outi. Zero DS ops.
__device__ __forceinline__ void wave_top3(float v0, int i0, float v1, int i1,
                                          float v2, int i2,
                                          float outv[3], int outi[3]) {
    const float NINF = -__builtin_inff();
    #pragma unroll
    for (int k = 0; k < 3; ++k) {
        float m = __int_as_float(
            __builtin_amdgcn_readlane(__float_as_int(wave_fmax_l63(v0)), 63));
        int my = (v0 == m) ? i0 : IMAX;
        int widx = __builtin_amdgcn_readlane(wave_imin_l63(my), 63);
        outv[k] = m; outi[k] = widx;
        if (v0 == m && i0 == widx) {   // owner pops its head
            v0 = v1; i0 = i1; v1 = v2; i1 = i2; v2 = NINF; i2 = IMAX;
        }
    }
}

__device__ __forceinline__ bool better(float av, int ai, float bv, int bi) {
    return (av > bv) || (av == bv && ai < bi);
}

__device__ __forceinline__ void merge3(float cv, int ci,
                                       float& v0, int& i0,
                                       float& v1, int& i1,
                                       float& v2, int& i2) {
    if (better(cv, ci, v2, i2)) {
        if (better(cv, ci, v1, i1)) {
            v2 = v1; i2 = i1;
            if (better(cv, ci, v0, i0)) { v1 = v0; i1 = i0; v0 = cv; i0 = ci; }
            else { v1 = cv; i1 = ci; }
        } else { v2 = cv; i2 = ci; }
    }
}

// One 64-lane wave per 16-row stripe. No LDS, no barriers, no DS ops.
// Thread owns 4 columns; halo via DPP; 4-row software pipeline of float4 loads.
__global__ __launch_bounds__(64) void peaks_phase1(const float* __restrict__ hm,
                                                   Cand* __restrict__ ws) {
    const int lane = threadIdx.x;
    const int g = blockIdx.x;              // global stripe id
    const int b = g / SPB;                 // batch (wave-uniform)
    const int s = g - b * SPB;
    const int r0 = s * RR;
    const float NINF = -__builtin_inff();

    const float* base = hm + (size_t)b * (size_t)(HTOT * W) + lane * 4;

    auto LOADROW = [&](int gr) -> float4 {
        float4 v;
        if ((unsigned)gr < (unsigned)HTOT) {
            v = *(const float4*)(base + (size_t)gr * W);
        } else {
            v.x = NINF; v.y = NINF; v.z = NINF; v.w = NINF;
        }
        return v;
    };

    float h[5][4];
    float raw0[4], raw1[4], raw2[4];
    #pragma unroll
    for (int k = 0; k < 5; ++k) {
        h[k][0] = NINF; h[k][1] = NINF; h[k][2] = NINF; h[k][3] = NINF;
    }
    #pragma unroll
    for (int j = 0; j < 4; ++j) { raw0[j] = NINF; raw1[j] = NINF; raw2[j] = NINF; }

    float v0 = NINF, v1 = NINF, v2 = NINF;
    int   i0 = IMAX, i1 = IMAX, i2 = IMAX;

    float4 p0 = LOADROW(r0 - 2);
    float4 p1 = LOADROW(r0 - 1);
    float4 p2 = LOADROW(r0);
    float4 p3 = LOADROW(r0 + 1);

    #pragma unroll
    for (int r = 0; r < RR + 4; ++r) {
        float4 cur = p0;
        p0 = p1; p1 = p2; p2 = p3;
        if (r < RR) p3 = LOADROW(r0 + 2 + r);

        // halo via DPP (boundary lanes auto-fill -inf; full-W stripe so image
        // edge == wave edge)
        float L1 = lane_up1(cur.w);
        float L2 = lane_up1(cur.z);
        float R1 = lane_dn1(cur.x);
        float R2 = lane_dn1(cur.y);

        float myz   = fmaxf(cur.y, cur.z);
        float mxyz  = fmaxf(cur.x, myz);
        float myzw  = fmaxf(myz, cur.w);
        float mxyzw = fmaxf(mxyz, cur.w);
        float hm0 = fmaxf(fmaxf(L2, L1), mxyz);
        float hm1 = fmaxf(L1, mxyzw);
        float hm2 = fmaxf(mxyzw, R1);
        float hm3 = fmaxf(myzw, fmaxf(R1, R2));

        #pragma unroll
        for (int k = 0; k < 4; ++k) {
            h[k][0] = h[k + 1][0]; h[k][1] = h[k + 1][1];
            h[k][2] = h[k + 1][2]; h[k][3] = h[k + 1][3];
        }
        h[4][0] = hm0; h[4][1] = hm1; h[4][2] = hm2; h[4][3] = hm3;
        #pragma unroll
        for (int j = 0; j < 4; ++j) { raw0[j] = raw1[j]; raw1[j] = raw2[j]; }
        raw2[0] = cur.x; raw2[1] = cur.y; raw2[2] = cur.z; raw2[3] = cur.w;

        if (r >= 4) {
            const int rout = r0 + r - 4;
            #pragma unroll
            for (int j = 0; j < 4; ++j) {
                float wmax = fmaxf(fmaxf(fmaxf(h[0][j], h[1][j]),
                                         fmaxf(h[2][j], h[3][j])), h[4][j]);
                float rv = raw0[j];
                // exact-equality peak test; strict > keeps earliest (smallest
                // index) equal value first within a thread.
                if (rv == wmax && rv > v2) {
                    int idx = rout * W + lane * 4 + j;
                    if (rv > v1) {
                        v2 = v1; i2 = i1;
                        if (rv > v0) { v1 = v0; i1 = i0; v0 = rv; i0 = idx; }
                        else         { v1 = rv; i1 = idx; }
                    } else { v2 = rv; i2 = idx; }
                }
            }
        }
    }

    // wave top-3 via DPP extraction (no DS)
    float outv[3]; int outi[3];
    wave_top3(v0, i0, v1, i1, v2, i2, outv, outi);

    if (lane == 0) {
        Cand* o = ws + (size_t)g * 3;
        o[0].v = outv[0]; o[0].i = outi[0];
        o[1].v = outv[1]; o[1].i = outi[1];
        o[2].v = outv[2]; o[2].i = outi[2];
    }
}

// One wave per batch: 240 candidates, 4 per lane, DPP extraction, no LDS.
__global__ __launch_bounds__(64) void peaks_phase2(const Cand* __restrict__ ws,
                                                   float* __restrict__ out) {
    const int b = blockIdx.x;
    const int t = threadIdx.x;
    const float NINF = -__builtin_inff();

    float v0 = NINF, v1 = NINF, v2 = NINF;
    int   i0 = IMAX, i1 = IMAX, i2 = IMAX;
    const Cand* src = ws + (size_t)b * NC;
    #pragma unroll
    for (int q = 0; q < 4; ++q) {
        int idx = q * 64 + t;           // coalesced; NC=240 so idx<NC for q<3, tail guarded
        if (idx < NC) {
            Cand e = src[idx];
            merge3(e.v, e.i, v0, i0, v1, i1, v2, i2);
        }
    }

    float outv[3]; int outi[3];
    wave_top3(v0, i0, v1, i1, v2, i2, outv, outi);

    if (t == 0) {
        // positions [64,3,3] at 0 ; scores [64,3] at 576 ; mask [64,3] at 768
        float* pos = out + (size_t)b * 9;
        float* sco = out + 576 + (size_t)b * 3;
        float* msk = out + 768 + (size_t)b * 3;
        #pragma unroll
        for (int k = 0; k < 3; ++k) {
            int idx = outi[k];
            pos[k * 3 + 0] = (float)(idx >> 16);
            pos[k * 3 + 1] = (float)((idx >> 8) & 255);
            pos[k * 3 + 2] = (float)(idx & 255);
            sco[k] = outv[k];
            msk[k] = (outv[k] > -1e30f) ? 1.0f : 0.0f;
        }
    }
}

extern "C" void kernel_launch(void* const* d_in, const int* in_sizes, int n_in,
                              void* d_out, int out_size, void* d_ws, size_t ws_size,
                              hipStream_t stream) {
    const float* hm = (const float*)d_in[0];
    float* out = (float*)d_out;
    Cand* ws = (Cand*)d_ws;  // 64*80*3*8 = 122880 bytes

    peaks_phase1<<<BS * SPB, 64, 0, stream>>>(hm, ws);   // 5120 one-wave blocks
    peaks_phase2<<<BS, 64, 0, stream>>>(ws, out);
}

// Round 7
// 30.997 us; speedup vs baseline: 1.8955x; 1.0118x over previous
//
#include <hip/hip_runtime.h>

#define W 256
#define HTOT 1280            // num_img * H = 5 * 256
#define RR 16                // output rows per wave
#define SPB (HTOT / RR)      // 80 stripes per batch
#define BS 64                // batch size
#define WPB 2                // independent waves per block (no barrier, no LDS)
#define NC (SPB * 3)         // 240 candidates per batch
#define NEG_FILL -1e9f

struct Cand { float v; int i; };

#define NINF_BITS ((int)0xFF800000)
#define IMAX 0x7fffffff

// ---------- DPP primitives (pure VALU, no DS, no LDS) ----------
// wave_shr:1 (0x138): lane i <- lane i-1 ; invalid lanes get `old` (-inf).
// wave_shl:1 (0x130): lane i <- lane i+1.
__device__ __forceinline__ float lane_up1(float x) {
    return __int_as_float(__builtin_amdgcn_update_dpp(
        NINF_BITS, __float_as_int(x), 0x138, 0xF, 0xF, false));
}
__device__ __forceinline__ float lane_dn1(float x) {
    return __int_as_float(__builtin_amdgcn_update_dpp(
        NINF_BITS, __float_as_int(x), 0x130, 0xF, 0xF, false));
}

template <int CTRL>
__device__ __forceinline__ float fmax_dpp(float x) {
    int s = __builtin_amdgcn_update_dpp(NINF_BITS, __float_as_int(x),
                                        CTRL, 0xF, 0xF, false);
    return fmaxf(x, __int_as_float(s));
}
template <int CTRL>
__device__ __forceinline__ int imin_dpp(int x) {
    int s = __builtin_amdgcn_update_dpp(IMAX, x, CTRL, 0xF, 0xF, false);
    return (s < x) ? s : x;
}

// wave64 max -> lane 63 (row_shr 1,2,4,8 then row_bcast15, row_bcast31)
__device__ __forceinline__ float wave_fmax_l63(float x) {
    x = fmax_dpp<0x111>(x);
    x = fmax_dpp<0x112>(x);
    x = fmax_dpp<0x114>(x);
    x = fmax_dpp<0x118>(x);
    x = fmax_dpp<0x142>(x);
    x = fmax_dpp<0x143>(x);
    return x;
}
__device__ __forceinline__ int wave_imin_l63(int x) {
    x = imin_dpp<0x111>(x);
    x = imin_dpp<0x112>(x);
    x = imin_dpp<0x114>(x);
    x = imin_dpp<0x118>(x);
    x = imin_dpp<0x142>(x);
    x = imin_dpp<0x143>(x);
    return x;
}

// Extract wave-wide top-3 from per-thread sorted lists (v0>=v1>=v2, index
// tie-break: within a thread v0 holds the smallest index among equals).
// Results are wave-uniform in outv/outi. Zero DS ops.
__device__ __forceinline__ void wave_top3(float v0, int i0, float v1, int i1,
                                          float v2, int i2,
                                          float outv[3], int outi[3]) {
    const float NINF = -__builtin_inff();
    #pragma unroll
    for (int k = 0; k < 3; ++k) {
        float m = __int_as_float(
            __builtin_amdgcn_readlane(__float_as_int(wave_fmax_l63(v0)), 63));
        int my = (v0 == m) ? i0 : IMAX;
        int widx = __builtin_amdgcn_readlane(wave_imin_l63(my), 63);
        outv[k] = m; outi[k] = widx;
        if (v0 == m && i0 == widx) {   // owner pops its head
            v0 = v1; i0 = i1; v1 = v2; i1 = i2; v2 = NINF; i2 = IMAX;
        }
    }
}

__device__ __forceinline__ bool better(float av, int ai, float bv, int bi) {
    return (av > bv) || (av == bv && ai < bi);
}

__device__ __forceinline__ void merge3(float cv, int ci,
                                       float& v0, int& i0,
                                       float& v1, int& i1,
                                       float& v2, int& i2) {
    if (better(cv, ci, v2, i2)) {
        if (better(cv, ci, v1, i1)) {
            v2 = v1; i2 = i1;
            if (better(cv, ci, v0, i0)) { v1 = v0; i1 = i0; v0 = cv; i0 = ci; }
            else { v1 = cv; i1 = ci; }
        } else { v2 = cv; i2 = ci; }
    }
}

// Two independent 64-lane waves per 128-thread block; each wave owns one
// 16-row stripe. No LDS, no barriers, no DS ops. Thread owns 4 columns;
// halo via DPP; 4-row software pipeline of float4 loads.
__global__ __launch_bounds__(64 * WPB) void peaks_phase1(const float* __restrict__ hm,
                                                         Cand* __restrict__ ws) {
    const int lane = threadIdx.x & 63;
    const int wv   = threadIdx.x >> 6;
    const int g = blockIdx.x * WPB + wv;   // global stripe id (2 | 80 -> no batch straddle)
    const int b = g / SPB;                 // batch (wave-uniform)
    const int s = g - b * SPB;
    const int r0 = s * RR;
    const float NINF = -__builtin_inff();

    const float* base = hm + (size_t)b * (size_t)(HTOT * W) + lane * 4;

    auto LOADROW = [&](int gr) -> float4 {
        float4 v;
        if ((unsigned)gr < (unsigned)HTOT) {
            v = *(const float4*)(base + (size_t)gr * W);
        } else {
            v.x = NINF; v.y = NINF; v.z = NINF; v.w = NINF;
        }
        return v;
    };

    float h[5][4];
    float raw0[4], raw1[4], raw2[4];
    #pragma unroll
    for (int k = 0; k < 5; ++k) {
        h[k][0] = NINF; h[k][1] = NINF; h[k][2] = NINF; h[k][3] = NINF;
    }
    #pragma unroll
    for (int j = 0; j < 4; ++j) { raw0[j] = NINF; raw1[j] = NINF; raw2[j] = NINF; }

    float v0 = NINF, v1 = NINF, v2 = NINF;
    int   i0 = IMAX, i1 = IMAX, i2 = IMAX;

    float4 p0 = LOADROW(r0 - 2);
    float4 p1 = LOADROW(r0 - 1);
    float4 p2 = LOADROW(r0);
    float4 p3 = LOADROW(r0 + 1);

    #pragma unroll
    for (int r = 0; r < RR + 4; ++r) {
        float4 cur = p0;
        p0 = p1; p1 = p2; p2 = p3;
        if (r < RR) p3 = LOADROW(r0 + 2 + r);

        // halo via DPP (boundary lanes auto-fill -inf; full-W stripe so image
        // edge == wave edge)
        float L1 = lane_up1(cur.w);
        float L2 = lane_up1(cur.z);
        float R1 = lane_dn1(cur.x);
        float R2 = lane_dn1(cur.y);

        float myz   = fmaxf(cur.y, cur.z);
        float mxyz  = fmaxf(cur.x, myz);
        float myzw  = fmaxf(myz, cur.w);
        float mxyzw = fmaxf(mxyz, cur.w);
        float hm0 = fmaxf(fmaxf(L2, L1), mxyz);
        float hm1 = fmaxf(L1, mxyzw);
        float hm2 = fmaxf(mxyzw, R1);
        float hm3 = fmaxf(myzw, fmaxf(R1, R2));

        #pragma unroll
        for (int k = 0; k < 4; ++k) {
            h[k][0] = h[k + 1][0]; h[k][1] = h[k + 1][1];
            h[k][2] = h[k + 1][2]; h[k][3] = h[k + 1][3];
        }
        h[4][0] = hm0; h[4][1] = hm1; h[4][2] = hm2; h[4][3] = hm3;
        #pragma unroll
        for (int j = 0; j < 4; ++j) { raw0[j] = raw1[j]; raw1[j] = raw2[j]; }
        raw2[0] = cur.x; raw2[1] = cur.y; raw2[2] = cur.z; raw2[3] = cur.w;

        if (r >= 4) {
            const int rout = r0 + r - 4;
            #pragma unroll
            for (int j = 0; j < 4; ++j) {
                float rv = raw0[j];
                // cheap filter first: only compute/compare window max when this
                // value could enter the top-3 (same conjunction, reordered).
                if (rv > v2) {
                    float wmax = fmaxf(fmaxf(fmaxf(h[0][j], h[1][j]),
                                             fmaxf(h[2][j], h[3][j])), h[4][j]);
                    if (rv == wmax) {
                        int idx = rout * W + lane * 4 + j;
                        if (rv > v1) {
                            v2 = v1; i2 = i1;
                            if (rv > v0) { v1 = v0; i1 = i0; v0 = rv; i0 = idx; }
                            else         { v1 = rv; i1 = idx; }
                        } else { v2 = rv; i2 = idx; }
                    }
                }
            }
        }
    }

    // wave top-3 via DPP extraction (no DS)
    float outv[3]; int outi[3];
    wave_top3(v0, i0, v1, i1, v2, i2, outv, outi);

    if (lane == 0) {
        Cand* o = ws + (size_t)g * 3;
        o[0].v = outv[0]; o[0].i = outi[0];
        o[1].v = outv[1]; o[1].i = outi[1];
        o[2].v = outv[2]; o[2].i = outi[2];
    }
}

// One wave per batch: 240 candidates, 4 per lane, DPP extraction, no LDS.
__global__ __launch_bounds__(64) void peaks_phase2(const Cand* __restrict__ ws,
                                                   float* __restrict__ out) {
    const int b = blockIdx.x;
    const int t = threadIdx.x;
    const float NINF = -__builtin_inff();

    float v0 = NINF, v1 = NINF, v2 = NINF;
    int   i0 = IMAX, i1 = IMAX, i2 = IMAX;
    const Cand* src = ws + (size_t)b * NC;
    #pragma unroll
    for (int q = 0; q < 4; ++q) {
        int idx = q * 64 + t;           // coalesced; tail guarded (NC=240)
        if (idx < NC) {
            Cand e = src[idx];
            merge3(e.v, e.i, v0, i0, v1, i1, v2, i2);
        }
    }

    float outv[3]; int outi[3];
    wave_top3(v0, i0, v1, i1, v2, i2, outv, outi);

    if (t == 0) {
        // positions [64,3,3] at 0 ; scores [64,3] at 576 ; mask [64,3] at 768
        float* pos = out + (size_t)b * 9;
        float* sco = out + 576 + (size_t)b * 3;
        float* msk = out + 768 + (size_t)b * 3;
        #pragma unroll
        for (int k = 0; k < 3; ++k) {
            int idx = outi[k];
            pos[k * 3 + 0] = (float)(idx >> 16);
            pos[k * 3 + 1] = (float)((idx >> 8) & 255);
            pos[k * 3 + 2] = (float)(idx & 255);
            sco[k] = outv[k];
            msk[k] = (outv[k] > -1e30f) ? 1.0f : 0.0f;
        }
    }
}

extern "C" void kernel_launch(void* const* d_in, const int* in_sizes, int n_in,
                              void* d_out, int out_size, void* d_ws, size_t ws_size,
                              hipStream_t stream) {
    const float* hm = (const float*)d_in[0];
    float* out = (float*)d_out;
    Cand* ws = (Cand*)d_ws;  // 64*80*3*8 = 122880 bytes

    peaks_phase1<<<(BS * SPB) / WPB, 64 * WPB, 0, stream>>>(hm, ws);
    peaks_phase2<<<BS, 64, 0, stream>>>(ws, out);
}